// Round 18
// baseline (160.163 us; speedup 1.0000x reference)
//
#include <hip/hip_runtime.h>
#include <hip/hip_bf16.h>

#define BB 4
#define CINsz 512
#define HH 63
#define NN 3969          // 63*63
#define NPAD 4032        // 63*64
#define NPAD2 4096       // q-row padding for 128-row tiles
#define CI 256
#define CO 512
#define NK 81
#define NKP 96           // padded k-dim
#define SCALE 0.0625f    // 256^-0.5 (folded into qk as 0.25 per operand)
#define BN_EPS 1e-5f
#define NSPLIT 4         // KV splits (R12 proven config)

typedef __bf16 bf16x8 __attribute__((ext_vector_type(8)));
typedef float f32x4 __attribute__((ext_vector_type(4)));
typedef unsigned short us8 __attribute__((ext_vector_type(8)));
typedef unsigned short us4 __attribute__((ext_vector_type(4)));

#define MFMA16(a, b, c) __builtin_amdgcn_mfma_f32_16x16x32_bf16((a), (b), (c), 0, 0, 0)

__device__ inline unsigned short f2bf(float x) {
    union { float f; unsigned int u; } v; v.f = x;
    unsigned int r = v.u + 0x7FFF + ((v.u >> 16) & 1);
    return (unsigned short)(r >> 16);
}
__device__ inline float bf2f(unsigned short u) {
    union { unsigned int u; float f; } v; v.u = ((unsigned int)u) << 16;
    return v.f;
}

// async global->LDS, 16B per lane, linear LDS dest (wave-uniform base + lane*16)
__device__ inline void gll16(const void* g, void* l) {
    __builtin_amdgcn_global_load_lds(
        (const __attribute__((address_space(1))) unsigned int*)g,
        (__attribute__((address_space(3))) unsigned int*)l, 16, 0, 0);
}

// ---------------- k_prep: weights -> bf16, BN folded into Wk; + zero qkbf pad rows ------------
__global__ __launch_bounds__(256) void k_prep(
    const float* __restrict__ Wk, const float* __restrict__ bk,
    const float* __restrict__ gamma, const float* __restrict__ beta,
    const float* __restrict__ Wv, const float* __restrict__ bv,
    const float* __restrict__ Wv2, const float* __restrict__ Ww,
    unsigned short* __restrict__ Wkv, float* __restrict__ bias2,
    unsigned short* __restrict__ Wv2b, unsigned short* __restrict__ Wwb,
    unsigned short* __restrict__ qkbf)
{
    int idx = blockIdx.x * 256 + threadIdx.x;
    if (idx < 512 * 512) {
        int o = idx >> 9, c = idx & 511;
        float v;
        if (o < 256) { float s = gamma[o] * rsqrtf(1.f + BN_EPS); v = Wk[(size_t)o * 512 + c] * s; }
        else v = Wv[(size_t)(o - 256) * 512 + c];
        Wkv[idx] = f2bf(v);
        if (c == 0) {
            bias2[o] = (o < 256) ? (bk[o] * (gamma[o] * rsqrtf(1.f + BN_EPS)) + beta[o]) : bv[o - 256];
        }
    } else if (idx < 512 * 512 + 256 * 256) {
        int j = idx - 512 * 512;
        Wv2b[j] = f2bf(Wv2[j]);
    } else if (idx < 512 * 512 + 256 * 256 + 512 * 256) {
        int j = idx - 512 * 512 - 256 * 256;
        Wwb[j] = f2bf(Ww[j]);
    } else if (idx < 512 * 512 + 256 * 256 + 512 * 256 + 8192) {
        int j = idx - (512 * 512 + 256 * 256 + 512 * 256);
        int b = j >> 11, rem = j & 2047;
        us8 z = (us8){0, 0, 0, 0, 0, 0, 0, 0};
        *reinterpret_cast<us8*>(&qkbf[(size_t)b * NPAD2 * CI + (size_t)NPAD * CI + rem * 8]) = z;
    }
}

// ---------------- k_qkv: x fp32 [b][c][n] -> qkbf (x0.25) / value bf16 ----------------
__global__ __launch_bounds__(256) void k_qkv(const float* __restrict__ x,
                                             const unsigned short* __restrict__ Wkv,
                                             const float* __restrict__ bias2,
                                             unsigned short* __restrict__ qkbf,
                                             unsigned short* __restrict__ value)
{
    int b = blockIdx.y;
    int nbase = blockIdx.x * 32;
    int tid = threadIdx.x, w = tid >> 6, lane = tid & 63, lg = lane >> 4, lr = lane & 15;
    int half = w >> 1;
    int o_off = half * 256;
    int nloc = (w & 1) * 16 + lr;       // local n index of this lane's A-rows

    __shared__ unsigned short xs[256 * 34];   // 17.4KB bf16, per c-half, stride 34
    __shared__ unsigned short wk[512 * 32];   // 32KB Wkv chunk [512 o][32 c]

    f32x4 acc[16];
#pragma unroll
    for (int t = 0; t < 16; ++t) acc[t] = (f32x4){0.f, 0.f, 0.f, 0.f};

    int n_l = tid & 31, cg = tid >> 5;  // staging coords
    int n_g = nbase + n_l;
    bool nok = n_g < NN;

    for (int h = 0; h < 2; ++h) {
        __syncthreads();   // xs of previous half fully consumed
        const float* xsrc = x + ((size_t)b * CINsz + h * 256 + cg) * NN + n_g;
#pragma unroll
        for (int i = 0; i < 32; ++i) {
            int cl = cg + i * 8;
            xs[cl * 34 + n_l] = nok ? f2bf(xsrc[(size_t)(i * 8) * NN]) : (unsigned short)0;
        }
        for (int s8 = 0; s8 < 8; ++s8) {
            int c0 = (h * 8 + s8) * 32;
            __syncthreads();   // prev chunk consumed; (s8==0: xs writes done)
#pragma unroll
            for (int j = 0; j < 8; ++j) {
                int o = w * 128 + j * 16 + (lane >> 2);
                int slot = (lane & 3) ^ (o & 3);   // pre-swizzled source
                gll16(Wkv + (size_t)o * CINsz + c0 + slot * 8,
                      &wk[(w * 128 + j * 16) * 32]);
            }
            __syncthreads();   // drain: chunk resident
            bf16x8 af;
#pragma unroll
            for (int j2 = 0; j2 < 8; ++j2)
                af[j2] = __builtin_bit_cast(__bf16, xs[(s8 * 32 + lg * 8 + j2) * 34 + nloc]);
            __builtin_amdgcn_s_setprio(1);
#pragma unroll
            for (int t = 0; t < 16; ++t) {
                int o_loc = o_off + t * 16 + lr;
                bf16x8 bf = *reinterpret_cast<const bf16x8*>(
                    &wk[o_loc * 32 + ((lg ^ (o_loc & 3)) << 3)]);
                acc[t] = MFMA16(af, bf, acc[t]);
            }
            __builtin_amdgcn_s_setprio(0);
        }
    }
    if (half == 0) {
        unsigned short* dst = qkbf + (size_t)b * NPAD2 * CI;
#pragma unroll
        for (int t = 0; t < 16; ++t) {
            int o = t * 16 + lr;
            float bsum = bias2[o];
#pragma unroll
            for (int r = 0; r < 4; ++r) {
                int n = nbase + (w & 1) * 16 + lg * 4 + r;
                dst[(size_t)n * CI + o] = f2bf((acc[t][r] + bsum) * 0.25f);  // sqrt(SCALE) fold
            }
        }
    } else {
        unsigned short* dst = value + (size_t)b * NPAD * CI;
#pragma unroll
        for (int t = 0; t < 16; ++t) {
            int o = t * 16 + lr;
            float bsum = bias2[256 + o];
#pragma unroll
            for (int r = 0; r < 4; ++r) {
                int n = nbase + (w & 1) * 16 + lg * 4 + r;
                dst[(size_t)n * CI + o] = f2bf(acc[t][r] + bsum);
            }
        }
    }
}

// ---------------- k_pool ----------------
__global__ __launch_bounds__(256) void k_pool(const unsigned short* __restrict__ value,
                                              unsigned short* __restrict__ pooled)
{
    int b = blockIdx.y, k = blockIdx.x, c = threadIdx.x;
    unsigned short* dst = pooled + ((size_t)b * NKP + k) * CI + c;
    if (k >= NK) { *dst = 0; return; }
    int ky = k / 9, kx = k % 9;
    const unsigned short* vb = value + (size_t)b * NPAD * CI + c;
    float s = 0.f;
#pragma unroll
    for (int y = 0; y < 7; ++y)
#pragma unroll
        for (int xx = 0; xx < 7; ++xx) {
            int n = (ky * 7 + y) * HH + kx * 7 + xx;
            s += bf2f(vb[(size_t)n * CI]);
        }
    *dst = f2bf(s * (1.f / 49.f));
}

// ---------------- k_v2 ----------------
__global__ __launch_bounds__(256) void k_v2(const unsigned short* __restrict__ pooled,
                                            const unsigned short* __restrict__ Wv2b,
                                            const float* __restrict__ bv2,
                                            unsigned short* __restrict__ v2f)
{
    int b = blockIdx.y;
    int tid = threadIdx.x, w = tid >> 6, lane = tid & 63, lg = lane >> 4, lr = lane & 15;
    int ot = blockIdx.x * 4 + w;
    const unsigned short* pb = pooled + (size_t)b * NKP * CI + lg * 8;
    const unsigned short* wb = Wv2b + (size_t)(ot * 16 + lr) * CI + lg * 8;
    f32x4 acc[6];
#pragma unroll
    for (int kt = 0; kt < 6; ++kt) acc[kt] = (f32x4){0.f, 0.f, 0.f, 0.f};
#pragma unroll
    for (int s = 0; s < 8; ++s) {
        bf16x8 bfw = *reinterpret_cast<const bf16x8*>(wb + s * 32);
#pragma unroll
        for (int kt = 0; kt < 6; ++kt) {
            bf16x8 af = *reinterpret_cast<const bf16x8*>(pb + (size_t)(kt * 16 + lr) * CI + s * 32);
            acc[kt] = MFMA16(af, bfw, acc[kt]);
        }
    }
    float bias = bv2[ot * 16 + lr];
#pragma unroll
    for (int kt = 0; kt < 6; ++kt)
#pragma unroll
        for (int r = 0; r < 4; ++r)
            v2f[((size_t)b * NKP + kt * 16 + lg * 4 + r) * CI + ot * 16 + lr] = f2bf(acc[kt][r] + bias);
}

// ---------------- k_Z ----------------
__global__ __launch_bounds__(256) void k_Z(const unsigned short* __restrict__ Wwb,
                                           const unsigned short* __restrict__ v2f,
                                           unsigned short* __restrict__ Zt)
{
    int b = blockIdx.y;
    int tid = threadIdx.x, w = tid >> 6, lane = tid & 63, lg = lane >> 4, lr = lane & 15;
    int ot = blockIdx.x * 4 + w;
    const unsigned short* wb = Wwb + (size_t)(ot * 16 + lr) * CI + lg * 8;
    const unsigned short* vb = v2f + (size_t)b * NKP * CI + lg * 8;
    f32x4 acc[6];
#pragma unroll
    for (int kt = 0; kt < 6; ++kt) acc[kt] = (f32x4){0.f, 0.f, 0.f, 0.f};
#pragma unroll
    for (int s = 0; s < 8; ++s) {
        bf16x8 af = *reinterpret_cast<const bf16x8*>(wb + s * 32);
#pragma unroll
        for (int kt = 0; kt < 6; ++kt) {
            bf16x8 bfv = *reinterpret_cast<const bf16x8*>(vb + (size_t)(kt * 16 + lr) * CI + s * 32);
            acc[kt] = MFMA16(af, bfv, acc[kt]);
        }
    }
#pragma unroll
    for (int kt = 0; kt < 6; ++kt)
#pragma unroll
        for (int r = 0; r < 4; ++r)
            Zt[((size_t)b * CO + ot * 16 + lg * 4 + r) * NKP + kt * 16 + lr] = f2bf(acc[kt][r]);
}

// ---------------- k_simv: v2f staged in LDS (48KB, swizzled); softmax rows; svT row 81 = 1.0 ---
__global__ __launch_bounds__(256) void k_simv(const unsigned short* __restrict__ value,
                                              const unsigned short* __restrict__ v2f,
                                              unsigned short* __restrict__ svT)
{
    int b = blockIdx.y;
    int tid = threadIdx.x, w = tid >> 6, lane = tid & 63, lg = lane >> 4, lr = lane & 15;
    int n0 = blockIdx.x * 64 + w * 16;

    __shared__ unsigned short sv[96 * 256];   // 48KB, XOR-swizzled rows

    // stage v2f batch slice: 48 x 1KB loads (2 rows each), wave w does 12
    const unsigned short* v2base = v2f + (size_t)b * NKP * CI;
#pragma unroll
    for (int j = 0; j < 12; ++j) {
        int L = w * 12 + j;
        int row = 2 * L + (lane >> 5);
        int c_hw = ((lane & 31) * 8) ^ ((row & 7) << 3);
        gll16(v2base + (size_t)row * CI + c_hw, &sv[2 * L * 256]);
    }
    __syncthreads();   // drain + all staged

    const unsigned short* vrow = value + ((size_t)b * NPAD + n0 + lr) * CI + lg * 8;
    f32x4 acc[6];
#pragma unroll
    for (int kt = 0; kt < 6; ++kt) acc[kt] = (f32x4){0.f, 0.f, 0.f, 0.f};
#pragma unroll
    for (int s = 0; s < 8; ++s) {
        bf16x8 af = *reinterpret_cast<const bf16x8*>(vrow + s * 32);
        __builtin_amdgcn_s_setprio(1);
#pragma unroll
        for (int kt = 0; kt < 6; ++kt) {
            int row = kt * 16 + lr;
            bf16x8 bfv = *reinterpret_cast<const bf16x8*>(
                &sv[row * 256 + ((s * 32 + lg * 8) ^ ((row & 7) << 3))]);
            acc[kt] = MFMA16(af, bfv, acc[kt]);
        }
        __builtin_amdgcn_s_setprio(0);
    }
#pragma unroll
    for (int kt = 0; kt < 6; ++kt) {
        bool bad = (kt * 16 + lr) >= NK;
#pragma unroll
        for (int r = 0; r < 4; ++r) acc[kt][r] = bad ? -1e30f : acc[kt][r] * SCALE;
    }
#pragma unroll
    for (int r = 0; r < 4; ++r) {
        float m = acc[0][r];
#pragma unroll
        for (int kt = 1; kt < 6; ++kt) m = fmaxf(m, acc[kt][r]);
#pragma unroll
        for (int off = 1; off < 16; off <<= 1) m = fmaxf(m, __shfl_xor(m, off));
        float p[6], sum = 0.f;
#pragma unroll
        for (int kt = 0; kt < 6; ++kt) { p[kt] = __expf(acc[kt][r] - m); sum += p[kt]; }
#pragma unroll
        for (int off = 1; off < 16; off <<= 1) sum += __shfl_xor(sum, off);
        float inv = 1.f / sum;
#pragma unroll
        for (int kt = 0; kt < 6; ++kt) acc[kt][r] = p[kt] * inv;
    }
#pragma unroll
    for (int kt = 0; kt < 6; ++kt) {
        us4 pk;
#pragma unroll
        for (int r = 0; r < 4; ++r) pk[r] = f2bf(acc[kt][r]);
        if (kt * 16 + lr == 81) { pk[0] = pk[1] = pk[2] = pk[3] = 0x3F80; }  // ones column
        *reinterpret_cast<us4*>(&svT[((size_t)b * NKP + kt * 16 + lr) * NPAD + n0 + lg * 4]) = pk;
    }
}

// ---------------- k_flash: R15 structure + counted-vmcnt bar1 (T4, no register prefetch) ------
// grid 512, 64-key tiles, 76KB LDS, 2 blocks/CU. bar1 retires SV loads only (vmcnt(8));
// the 8 K-prefetch loads stay in flight until bar2's full drain.
__global__ __launch_bounds__(256, 2) void k_flash(const unsigned short* __restrict__ qkbf,
                                                  const unsigned short* __restrict__ svT,
                                                  unsigned short* __restrict__ part_acc,
                                                  float* __restrict__ part_ml)
{
    int bid = blockIdx.x;
    int b = bid & 3;
    int rest = bid >> 2;
    int qg = rest & 31;
    int s_id = rest >> 5;              // 0..3
    int lo = s_id * 16;
    int hi = lo + 16 > 63 ? 63 : lo + 16;
    int tid = threadIdx.x, w = tid >> 6, lane = tid & 63, lg = lane >> 4, lr = lane & 15;
    int q0 = qg * 128 + w * 16;        // sub u adds u*64

    __shared__ unsigned short k_lds[2][64 * 256];   // 32KB each; rows reused as P post-bar1
    __shared__ unsigned short sv_lds[96 * 64];      // 12KB single

    const unsigned short* qkb = qkbf + (size_t)b * NPAD2 * CI;
    const unsigned short* svb = svT + (size_t)b * NKP * NPAD;

    bf16x8 qa[2][8];
#pragma unroll
    for (int u = 0; u < 2; ++u)
#pragma unroll
        for (int s = 0; s < 8; ++s)
            qa[u][s] = *reinterpret_cast<const bf16x8*>(
                qkb + (size_t)(q0 + u * 64 + lr) * CI + s * 32 + lg * 8);

    f32x4 acc[2][6];
#pragma unroll
    for (int u = 0; u < 2; ++u)
#pragma unroll
        for (int jt = 0; jt < 6; ++jt) acc[u][jt] = (f32x4){0.f, 0.f, 0.f, 0.f};
    float m_run[2][4];
#pragma unroll
    for (int u = 0; u < 2; ++u)
#pragma unroll
        for (int r = 0; r < 4; ++r) m_run[u][r] = -1e30f;

    auto stageK = [&](int t, int bi) {
#pragma unroll
        for (int j = 0; j < 8; ++j) {
            int r = w * 16 + j * 2 + (lane >> 5);
            int c_hw = ((lane & 31) * 8) ^ ((r & 7) << 3);
            gll16(qkb + (size_t)(t * 64 + r) * CI + c_hw,
                  &k_lds[bi][(w * 16 + j * 2) * 256]);
        }
    };
    auto stageSV = [&](int t) {
#pragma unroll
        for (int j = 0; j < 3; ++j) {
            int k = w * 24 + j * 8 + (lane >> 3);
            int m_hw = ((lane & 7) * 8) ^ ((k & 7) << 3);
            gll16(svb + (size_t)k * NPAD + t * 64 + m_hw,
                  &sv_lds[(w * 24 + j * 8) * 64]);
        }
    };

    stageK(lo, 0);
    stageSV(lo);
    __syncthreads();

    for (int t = lo; t < hi; ++t) {
        int bi = (t - lo) & 1;
        int mbase = t * 64;
        if (t + 1 < hi) stageK(t + 1, bi ^ 1);   // prefetch next K (other buffer)

        f32x4 s_acc[2][4];
#pragma unroll
        for (int u = 0; u < 2; ++u)
#pragma unroll
            for (int tt = 0; tt < 4; ++tt) s_acc[u][tt] = (f32x4){0.f, 0.f, 0.f, 0.f};
        __builtin_amdgcn_s_setprio(1);
#pragma unroll
        for (int s = 0; s < 8; ++s) {
            bf16x8 kf[4];
#pragma unroll
            for (int tt = 0; tt < 4; ++tt) {
                int row = tt * 16 + lr;
                int hw = (s * 32 + lg * 8) ^ ((row & 7) << 3);
                kf[tt] = *reinterpret_cast<const bf16x8*>(&k_lds[bi][row * 256 + hw]);
            }
#pragma unroll
            for (int tt = 0; tt < 4; ++tt) {
                s_acc[0][tt] = MFMA16(qa[0][s], kf[tt], s_acc[0][tt]);
                s_acc[1][tt] = MFMA16(qa[1][s], kf[tt], s_acc[1][tt]);
            }
        }
        __builtin_amdgcn_s_setprio(0);
        // ---- bar1 (counted): retire SV loads (3 oldest); K prefetch (8 newest) stays in flight
        asm volatile("s_waitcnt vmcnt(8) lgkmcnt(0)" ::: "memory");
        __builtin_amdgcn_s_barrier();
        __builtin_amdgcn_sched_barrier(0);

        unsigned short* pw = &k_lds[bi][w * 2048];    // 4KB per wave
        bool lastTile = (mbase + 64 > NN);
#pragma unroll
        for (int u = 0; u < 2; ++u) {
            if (lastTile) {
#pragma unroll
                for (int tt = 0; tt < 4; ++tt) {
                    bool bad = (mbase + tt * 16 + lr) >= NN;
#pragma unroll
                    for (int r = 0; r < 4; ++r) if (bad) s_acc[u][tt][r] = -1e30f;
                }
            }
            float pmax[4];
#pragma unroll
            for (int r = 0; r < 4; ++r) {
                float m0 = fmaxf(fmaxf(s_acc[u][0][r], s_acc[u][1][r]),
                                 fmaxf(s_acc[u][2][r], s_acc[u][3][r]));
#pragma unroll
                for (int off = 1; off < 16; off <<= 1) m0 = fmaxf(m0, __shfl_xor(m0, off));
                pmax[r] = m0;
            }
            bool ok = (pmax[0] - m_run[u][0] <= 8.f) && (pmax[1] - m_run[u][1] <= 8.f) &&
                      (pmax[2] - m_run[u][2] <= 8.f) && (pmax[3] - m_run[u][3] <= 8.f);
            if (!__all(ok)) {
#pragma unroll
                for (int r = 0; r < 4; ++r) {
                    float mn = fmaxf(m_run[u][r], pmax[r]);
                    float al = __expf(m_run[u][r] - mn);
                    m_run[u][r] = mn;
#pragma unroll
                    for (int jt = 0; jt < 6; ++jt) acc[u][jt][r] *= al;
                }
            }
            unsigned short* pu = pw + u * 1024;
#pragma unroll
            for (int tt = 0; tt < 4; ++tt) {
#pragma unroll
                for (int r = 0; r < 4; ++r) {
                    float p = __expf(s_acc[u][tt][r] - m_run[u][r]);
                    int row = lg * 4 + r, col = tt * 16 + lr;
                    pu[row * 64 + (col ^ ((row & 7) << 3))] = f2bf(p);
                }
            }
        }
        __builtin_amdgcn_s_setprio(1);
#pragma unroll
        for (int kb = 0; kb < 2; ++kb) {
            int hw = kb * 32 + lg * 8;
            int phw = hw ^ ((lr & 7) << 3);
            bf16x8 pa0 = *reinterpret_cast<const bf16x8*>(&pw[lr * 64 + phw]);
            bf16x8 pa1 = *reinterpret_cast<const bf16x8*>(&pw[1024 + lr * 64 + phw]);
#pragma unroll
            for (int jt = 0; jt < 6; ++jt) {
                int cr = jt * 16 + lr;
                bf16x8 svf = *reinterpret_cast<const bf16x8*>(
                    &sv_lds[cr * 64 + (hw ^ ((cr & 7) << 3))]);
                acc[0][jt] = MFMA16(pa0, svf, acc[0][jt]);
                acc[1][jt] = MFMA16(pa1, svf, acc[1][jt]);
            }
        }
        __builtin_amdgcn_s_setprio(0);
        __syncthreads();   // bar2: full drain — K prefetch retired; sv_lds + P consumed
        if (t + 1 < hi) stageSV(t + 1);   // lands during next QK^T, retired at next bar1
    }
    int plane = s_id * 4 + b;
    unsigned short* pa_out = part_acc + (size_t)plane * NPAD2 * 96;
    float* ml_out = part_ml + (size_t)plane * 2 * NPAD2;
#pragma unroll
    for (int u = 0; u < 2; ++u)
#pragma unroll
        for (int r = 0; r < 4; ++r) {
            int row = q0 + u * 64 + lg * 4 + r;
#pragma unroll
            for (int jt = 0; jt < 6; ++jt)
                pa_out[(size_t)row * 96 + jt * 16 + lr] = f2bf(acc[u][jt][r]);
            if (lr == 0) ml_out[row] = m_run[u][r];
            if (lr == 1) ml_out[NPAD2 + row] = acc[u][5][r];   // l = acc col 81 (fp32)
        }
}

// ---------------- k_out (fused merge, og-loop inside): 4-plane merge once, then 8x MFMA -------
__global__ __launch_bounds__(256) void k_out(const unsigned short* __restrict__ part_acc,
                                             const float* __restrict__ part_ml,
                                             const unsigned short* __restrict__ Zt,
                                             const float* __restrict__ bw,
                                             float* __restrict__ out)
{
    int b = blockIdx.y;
    int ng = blockIdx.x;
    int tid = threadIdx.x, w = tid >> 6, lane = tid & 63, lg = lane >> 4, lr = lane & 15;

    __shared__ unsigned short sn[64 * 104];   // 13.3KB, stride 104 (2-way banks = free)

    // ---- phase 1: split-softmax merge of 4 planes for rows ng*64..+63
    for (int j = tid; j < 768; j += 256) {
        int row_l = j / 12, ch = j - row_l * 12;
        int row = ng * 64 + row_l;
        float m_s[NSPLIT], l_s[NSPLIT];
        float mg = -1e30f;
#pragma unroll
        for (int s = 0; s < NSPLIT; ++s) {
            const float* ml = part_ml + (size_t)(s * 4 + b) * 2 * NPAD2;
            m_s[s] = ml[row]; l_s[s] = ml[NPAD2 + row];
            mg = fmaxf(mg, m_s[s]);
        }
        float f_s[NSPLIT], denom = 0.f;
#pragma unroll
        for (int s = 0; s < NSPLIT; ++s) { f_s[s] = __expf(m_s[s] - mg); denom += f_s[s] * l_s[s]; }
        float inv = 1.f / denom;
        float a[8];
#pragma unroll
        for (int q = 0; q < 8; ++q) a[q] = 0.f;
#pragma unroll
        for (int s = 0; s < NSPLIT; ++s) {
            us8 v = *reinterpret_cast<const us8*>(
                &part_acc[((size_t)(s * 4 + b) * NPAD2 + row) * 96 + ch * 8]);
#pragma unroll
            for (int q = 0; q < 8; ++q) a[q] += f_s[s] * bf2f(v[q]);
        }
        us8 o;
#pragma unroll
        for (int q = 0; q < 8; ++q) o[q] = f2bf(a[q] * inv);
        if (ch == 10) o[1] = 0;   // zero col 81 (the ones/l column)
        *reinterpret_cast<us8*>(&sn[row_l * 104 + ch * 8]) = o;
    }
    __syncthreads();

    // ---- phase 2: loop og: D[o][n] = sum_k Zt[o][k]*sn[n][k] + bw
    for (int og = 0; og < 8; ++og) {
        int o_row = (og * 4 + w) * 16;
        const unsigned short* za = Zt + ((size_t)b * CO + o_row + lr) * NKP + lg * 8;
        bf16x8 az[3];
#pragma unroll
        for (int ks = 0; ks < 3; ++ks) az[ks] = *reinterpret_cast<const bf16x8*>(za + ks * 32);
        f32x4 acc[4];
#pragma unroll
        for (int jn = 0; jn < 4; ++jn) acc[jn] = (f32x4){0.f, 0.f, 0.f, 0.f};
#pragma unroll
        for (int jn = 0; jn < 4; ++jn)
#pragma unroll
            for (int ks = 0; ks < 3; ++ks) {
                bf16x8 bfs = *reinterpret_cast<const bf16x8*>(
                    &sn[(jn * 16 + lr) * 104 + ks * 32 + lg * 8]);
                acc[jn] = MFMA16(az[ks], bfs, acc[jn]);
            }
#pragma unroll
        for (int r = 0; r < 4; ++r) {
            int o = o_row + lg * 4 + r;
            float bias = bw[o];
            float* orow = out + ((size_t)b * CO + o) * NN;
#pragma unroll
            for (int jn = 0; jn < 4; ++jn) {
                int n = ng * 64 + jn * 16 + lr;
                if (n < NN) orow[n] = acc[jn][r] + bias;
            }
        }
    }
}

extern "C" void kernel_launch(void* const* d_in, const int* in_sizes, int n_in,
                              void* d_out, int out_size, void* d_ws, size_t ws_size,
                              hipStream_t stream)
{
    const float* x     = (const float*)d_in[0];
    const float* Wk    = (const float*)d_in[1];
    const float* bk    = (const float*)d_in[2];
    const float* gamma = (const float*)d_in[3];
    const float* beta  = (const float*)d_in[4];
    const float* Wv    = (const float*)d_in[5];
    const float* bv    = (const float*)d_in[6];
    const float* Wv2   = (const float*)d_in[7];
    const float* bv2   = (const float*)d_in[8];
    const float* Ww    = (const float*)d_in[9];
    const float* bw    = (const float*)d_in[10];
    float* out = (float*)d_out;

    char* p = (char*)d_ws;
    unsigned short* qkbf   = (unsigned short*)p; p += (size_t)BB * NPAD2 * CI * 2;
    unsigned short* value  = (unsigned short*)p; p += (size_t)BB * NPAD * CI * 2;
    unsigned short* svT    = (unsigned short*)p; p += (size_t)BB * NKP * NPAD * 2;
    unsigned short* Wkv    = (unsigned short*)p; p += (size_t)512 * 512 * 2;
    unsigned short* Wv2b   = (unsigned short*)p; p += (size_t)256 * 256 * 2;
    unsigned short* Wwb    = (unsigned short*)p; p += (size_t)512 * 256 * 2;
    unsigned short* pooled = (unsigned short*)p; p += (size_t)BB * NKP * CI * 2;
    unsigned short* v2f    = (unsigned short*)p; p += (size_t)BB * NKP * CI * 2;
    unsigned short* Zt     = (unsigned short*)p; p += (size_t)BB * CO * NKP * 2;
    float* bias2           = (float*)p;          p += 512 * 4;
    unsigned short* part_acc = (unsigned short*)p; p += (size_t)16 * NPAD2 * 96 * 2;
    float* part_ml         = (float*)p;          p += (size_t)16 * 2 * NPAD2 * 4;

    k_prep<<<dim3(1826), 256, 0, stream>>>(Wk, bk, gamma, beta, Wv, bv, Wv2, Ww,
                                           Wkv, bias2, Wv2b, Wwb, qkbf);
    k_qkv<<<dim3(126, BB), 256, 0, stream>>>(x, Wkv, bias2, qkbf, value);
    k_pool<<<dim3(NKP, BB), 256, 0, stream>>>(value, pooled);
    k_v2<<<dim3(4, BB), 256, 0, stream>>>(pooled, Wv2b, bv2, v2f);
    k_Z<<<dim3(8, BB), 256, 0, stream>>>(Wwb, v2f, Zt);
    k_simv<<<dim3(63, BB), 256, 0, stream>>>(value, v2f, svT);
    k_flash<<<dim3(512), 256, 0, stream>>>(qkbf, svT, part_acc, part_ml);
    k_out<<<dim3(63, BB), 256, 0, stream>>>(part_acc, part_ml, Zt, bw, out);
}

// Round 19
// 158.160 us; speedup vs baseline: 1.0127x; 1.0127x over previous
//
#include <hip/hip_runtime.h>
#include <hip/hip_bf16.h>

#define BB 4
#define CINsz 512
#define HH 63
#define NN 3969          // 63*63
#define NPAD 4032        // 63*64
#define NPAD2 4096       // q-row padding for 128-row tiles
#define CI 256
#define CO 512
#define NK 81
#define NKP 96           // padded k-dim
#define SCALE 0.0625f    // 256^-0.5 (folded into qk as 0.25 per operand)
#define BN_EPS 1e-5f
#define NSPLIT 4         // KV splits (R12 proven config)

typedef __bf16 bf16x8 __attribute__((ext_vector_type(8)));
typedef float f32x4 __attribute__((ext_vector_type(4)));
typedef unsigned short us8 __attribute__((ext_vector_type(8)));
typedef unsigned short us4 __attribute__((ext_vector_type(4)));

#define MFMA16(a, b, c) __builtin_amdgcn_mfma_f32_16x16x32_bf16((a), (b), (c), 0, 0, 0)

__device__ inline unsigned short f2bf(float x) {
    union { float f; unsigned int u; } v; v.f = x;
    unsigned int r = v.u + 0x7FFF + ((v.u >> 16) & 1);
    return (unsigned short)(r >> 16);
}
__device__ inline float bf2f(unsigned short u) {
    union { unsigned int u; float f; } v; v.u = ((unsigned int)u) << 16;
    return v.f;
}

// async global->LDS, 16B per lane, linear LDS dest (wave-uniform base + lane*16)
__device__ inline void gll16(const void* g, void* l) {
    __builtin_amdgcn_global_load_lds(
        (const __attribute__((address_space(1))) unsigned int*)g,
        (__attribute__((address_space(3))) unsigned int*)l, 16, 0, 0);
}

// ---------------- k_prep: weights -> bf16, BN folded into Wk; + zero qkbf pad rows ------------
__global__ __launch_bounds__(256) void k_prep(
    const float* __restrict__ Wk, const float* __restrict__ bk,
    const float* __restrict__ gamma, const float* __restrict__ beta,
    const float* __restrict__ Wv, const float* __restrict__ bv,
    const float* __restrict__ Wv2, const float* __restrict__ Ww,
    unsigned short* __restrict__ Wkv, float* __restrict__ bias2,
    unsigned short* __restrict__ Wv2b, unsigned short* __restrict__ Wwb,
    unsigned short* __restrict__ qkbf)
{
    int idx = blockIdx.x * 256 + threadIdx.x;
    if (idx < 512 * 512) {
        int o = idx >> 9, c = idx & 511;
        float v;
        if (o < 256) { float s = gamma[o] * rsqrtf(1.f + BN_EPS); v = Wk[(size_t)o * 512 + c] * s; }
        else v = Wv[(size_t)(o - 256) * 512 + c];
        Wkv[idx] = f2bf(v);
        if (c == 0) {
            bias2[o] = (o < 256) ? (bk[o] * (gamma[o] * rsqrtf(1.f + BN_EPS)) + beta[o]) : bv[o - 256];
        }
    } else if (idx < 512 * 512 + 256 * 256) {
        int j = idx - 512 * 512;
        Wv2b[j] = f2bf(Wv2[j]);
    } else if (idx < 512 * 512 + 256 * 256 + 512 * 256) {
        int j = idx - 512 * 512 - 256 * 256;
        Wwb[j] = f2bf(Ww[j]);
    } else if (idx < 512 * 512 + 256 * 256 + 512 * 256 + 8192) {
        int j = idx - (512 * 512 + 256 * 256 + 512 * 256);
        int b = j >> 11, rem = j & 2047;
        us8 z = (us8){0, 0, 0, 0, 0, 0, 0, 0};
        *reinterpret_cast<us8*>(&qkbf[(size_t)b * NPAD2 * CI + (size_t)NPAD * CI + rem * 8]) = z;
    }
}

// ---------------- k_qkv: x fp32 [b][c][n] -> qkbf (x0.25) / value bf16 ----------------
__global__ __launch_bounds__(256) void k_qkv(const float* __restrict__ x,
                                             const unsigned short* __restrict__ Wkv,
                                             const float* __restrict__ bias2,
                                             unsigned short* __restrict__ qkbf,
                                             unsigned short* __restrict__ value)
{
    int b = blockIdx.y;
    int nbase = blockIdx.x * 32;
    int tid = threadIdx.x, w = tid >> 6, lane = tid & 63, lg = lane >> 4, lr = lane & 15;
    int half = w >> 1;
    int o_off = half * 256;
    int nloc = (w & 1) * 16 + lr;       // local n index of this lane's A-rows

    __shared__ unsigned short xs[256 * 34];   // 17.4KB bf16, per c-half, stride 34
    __shared__ unsigned short wk[512 * 32];   // 32KB Wkv chunk [512 o][32 c]

    f32x4 acc[16];
#pragma unroll
    for (int t = 0; t < 16; ++t) acc[t] = (f32x4){0.f, 0.f, 0.f, 0.f};

    int n_l = tid & 31, cg = tid >> 5;  // staging coords
    int n_g = nbase + n_l;
    bool nok = n_g < NN;

    for (int h = 0; h < 2; ++h) {
        __syncthreads();   // xs of previous half fully consumed
        const float* xsrc = x + ((size_t)b * CINsz + h * 256 + cg) * NN + n_g;
#pragma unroll
        for (int i = 0; i < 32; ++i) {
            int cl = cg + i * 8;
            xs[cl * 34 + n_l] = nok ? f2bf(xsrc[(size_t)(i * 8) * NN]) : (unsigned short)0;
        }
        for (int s8 = 0; s8 < 8; ++s8) {
            int c0 = (h * 8 + s8) * 32;
            __syncthreads();   // prev chunk consumed; (s8==0: xs writes done)
#pragma unroll
            for (int j = 0; j < 8; ++j) {
                int o = w * 128 + j * 16 + (lane >> 2);
                int slot = (lane & 3) ^ (o & 3);   // pre-swizzled source
                gll16(Wkv + (size_t)o * CINsz + c0 + slot * 8,
                      &wk[(w * 128 + j * 16) * 32]);
            }
            __syncthreads();   // drain: chunk resident
            bf16x8 af;
#pragma unroll
            for (int j2 = 0; j2 < 8; ++j2)
                af[j2] = __builtin_bit_cast(__bf16, xs[(s8 * 32 + lg * 8 + j2) * 34 + nloc]);
            __builtin_amdgcn_s_setprio(1);
#pragma unroll
            for (int t = 0; t < 16; ++t) {
                int o_loc = o_off + t * 16 + lr;
                bf16x8 bf = *reinterpret_cast<const bf16x8*>(
                    &wk[o_loc * 32 + ((lg ^ (o_loc & 3)) << 3)]);
                acc[t] = MFMA16(af, bf, acc[t]);
            }
            __builtin_amdgcn_s_setprio(0);
        }
    }
    if (half == 0) {
        unsigned short* dst = qkbf + (size_t)b * NPAD2 * CI;
#pragma unroll
        for (int t = 0; t < 16; ++t) {
            int o = t * 16 + lr;
            float bsum = bias2[o];
#pragma unroll
            for (int r = 0; r < 4; ++r) {
                int n = nbase + (w & 1) * 16 + lg * 4 + r;
                dst[(size_t)n * CI + o] = f2bf((acc[t][r] + bsum) * 0.25f);  // sqrt(SCALE) fold
            }
        }
    } else {
        unsigned short* dst = value + (size_t)b * NPAD * CI;
#pragma unroll
        for (int t = 0; t < 16; ++t) {
            int o = t * 16 + lr;
            float bsum = bias2[256 + o];
#pragma unroll
            for (int r = 0; r < 4; ++r) {
                int n = nbase + (w & 1) * 16 + lg * 4 + r;
                dst[(size_t)n * CI + o] = f2bf(acc[t][r] + bsum);
            }
        }
    }
}

// ---------------- k_pool ----------------
__global__ __launch_bounds__(256) void k_pool(const unsigned short* __restrict__ value,
                                              unsigned short* __restrict__ pooled)
{
    int b = blockIdx.y, k = blockIdx.x, c = threadIdx.x;
    unsigned short* dst = pooled + ((size_t)b * NKP + k) * CI + c;
    if (k >= NK) { *dst = 0; return; }
    int ky = k / 9, kx = k % 9;
    const unsigned short* vb = value + (size_t)b * NPAD * CI + c;
    float s = 0.f;
#pragma unroll
    for (int y = 0; y < 7; ++y)
#pragma unroll
        for (int xx = 0; xx < 7; ++xx) {
            int n = (ky * 7 + y) * HH + kx * 7 + xx;
            s += bf2f(vb[(size_t)n * CI]);
        }
    *dst = f2bf(s * (1.f / 49.f));
}

// ---------------- k_v2 ----------------
__global__ __launch_bounds__(256) void k_v2(const unsigned short* __restrict__ pooled,
                                            const unsigned short* __restrict__ Wv2b,
                                            const float* __restrict__ bv2,
                                            unsigned short* __restrict__ v2f)
{
    int b = blockIdx.y;
    int tid = threadIdx.x, w = tid >> 6, lane = tid & 63, lg = lane >> 4, lr = lane & 15;
    int ot = blockIdx.x * 4 + w;
    const unsigned short* pb = pooled + (size_t)b * NKP * CI + lg * 8;
    const unsigned short* wb = Wv2b + (size_t)(ot * 16 + lr) * CI + lg * 8;
    f32x4 acc[6];
#pragma unroll
    for (int kt = 0; kt < 6; ++kt) acc[kt] = (f32x4){0.f, 0.f, 0.f, 0.f};
#pragma unroll
    for (int s = 0; s < 8; ++s) {
        bf16x8 bfw = *reinterpret_cast<const bf16x8*>(wb + s * 32);
#pragma unroll
        for (int kt = 0; kt < 6; ++kt) {
            bf16x8 af = *reinterpret_cast<const bf16x8*>(pb + (size_t)(kt * 16 + lr) * CI + s * 32);
            acc[kt] = MFMA16(af, bfw, acc[kt]);
        }
    }
    float bias = bv2[ot * 16 + lr];
#pragma unroll
    for (int kt = 0; kt < 6; ++kt)
#pragma unroll
        for (int r = 0; r < 4; ++r)
            v2f[((size_t)b * NKP + kt * 16 + lg * 4 + r) * CI + ot * 16 + lr] = f2bf(acc[kt][r] + bias);
}

// ---------------- k_Z ----------------
__global__ __launch_bounds__(256) void k_Z(const unsigned short* __restrict__ Wwb,
                                           const unsigned short* __restrict__ v2f,
                                           unsigned short* __restrict__ Zt)
{
    int b = blockIdx.y;
    int tid = threadIdx.x, w = tid >> 6, lane = tid & 63, lg = lane >> 4, lr = lane & 15;
    int ot = blockIdx.x * 4 + w;
    const unsigned short* wb = Wwb + (size_t)(ot * 16 + lr) * CI + lg * 8;
    const unsigned short* vb = v2f + (size_t)b * NKP * CI + lg * 8;
    f32x4 acc[6];
#pragma unroll
    for (int kt = 0; kt < 6; ++kt) acc[kt] = (f32x4){0.f, 0.f, 0.f, 0.f};
#pragma unroll
    for (int s = 0; s < 8; ++s) {
        bf16x8 af = *reinterpret_cast<const bf16x8*>(wb + s * 32);
#pragma unroll
        for (int kt = 0; kt < 6; ++kt) {
            bf16x8 bfv = *reinterpret_cast<const bf16x8*>(vb + (size_t)(kt * 16 + lr) * CI + s * 32);
            acc[kt] = MFMA16(af, bfv, acc[kt]);
        }
    }
#pragma unroll
    for (int kt = 0; kt < 6; ++kt)
#pragma unroll
        for (int r = 0; r < 4; ++r)
            Zt[((size_t)b * CO + ot * 16 + lg * 4 + r) * NKP + kt * 16 + lr] = f2bf(acc[kt][r]);
}

// ---------------- k_simv: v2f staged in LDS (48KB, swizzled); softmax rows; svT row 81 = 1.0 ---
__global__ __launch_bounds__(256) void k_simv(const unsigned short* __restrict__ value,
                                              const unsigned short* __restrict__ v2f,
                                              unsigned short* __restrict__ svT)
{
    int b = blockIdx.y;
    int tid = threadIdx.x, w = tid >> 6, lane = tid & 63, lg = lane >> 4, lr = lane & 15;
    int n0 = blockIdx.x * 64 + w * 16;

    __shared__ unsigned short sv[96 * 256];   // 48KB, XOR-swizzled rows

    // stage v2f batch slice: 48 x 1KB loads (2 rows each), wave w does 12
    const unsigned short* v2base = v2f + (size_t)b * NKP * CI;
#pragma unroll
    for (int j = 0; j < 12; ++j) {
        int L = w * 12 + j;
        int row = 2 * L + (lane >> 5);
        int c_hw = ((lane & 31) * 8) ^ ((row & 7) << 3);
        gll16(v2base + (size_t)row * CI + c_hw, &sv[2 * L * 256]);
    }
    __syncthreads();   // drain + all staged

    const unsigned short* vrow = value + ((size_t)b * NPAD + n0 + lr) * CI + lg * 8;
    f32x4 acc[6];
#pragma unroll
    for (int kt = 0; kt < 6; ++kt) acc[kt] = (f32x4){0.f, 0.f, 0.f, 0.f};
#pragma unroll
    for (int s = 0; s < 8; ++s) {
        bf16x8 af = *reinterpret_cast<const bf16x8*>(vrow + s * 32);
        __builtin_amdgcn_s_setprio(1);
#pragma unroll
        for (int kt = 0; kt < 6; ++kt) {
            int row = kt * 16 + lr;
            bf16x8 bfv = *reinterpret_cast<const bf16x8*>(
                &sv[row * 256 + ((s * 32 + lg * 8) ^ ((row & 7) << 3))]);
            acc[kt] = MFMA16(af, bfv, acc[kt]);
        }
        __builtin_amdgcn_s_setprio(0);
    }
#pragma unroll
    for (int kt = 0; kt < 6; ++kt) {
        bool bad = (kt * 16 + lr) >= NK;
#pragma unroll
        for (int r = 0; r < 4; ++r) acc[kt][r] = bad ? -1e30f : acc[kt][r] * SCALE;
    }
#pragma unroll
    for (int r = 0; r < 4; ++r) {
        float m = acc[0][r];
#pragma unroll
        for (int kt = 1; kt < 6; ++kt) m = fmaxf(m, acc[kt][r]);
#pragma unroll
        for (int off = 1; off < 16; off <<= 1) m = fmaxf(m, __shfl_xor(m, off));
        float p[6], sum = 0.f;
#pragma unroll
        for (int kt = 0; kt < 6; ++kt) { p[kt] = __expf(acc[kt][r] - m); sum += p[kt]; }
#pragma unroll
        for (int off = 1; off < 16; off <<= 1) sum += __shfl_xor(sum, off);
        float inv = 1.f / sum;
#pragma unroll
        for (int kt = 0; kt < 6; ++kt) acc[kt][r] = p[kt] * inv;
    }
#pragma unroll
    for (int kt = 0; kt < 6; ++kt) {
        us4 pk;
#pragma unroll
        for (int r = 0; r < 4; ++r) pk[r] = f2bf(acc[kt][r]);
        if (kt * 16 + lr == 81) { pk[0] = pk[1] = pk[2] = pk[3] = 0x3F80; }  // ones column
        *reinterpret_cast<us4*>(&svT[((size_t)b * NKP + kt * 16 + lr) * NPAD + n0 + lg * 4]) = pk;
    }
}

// ---------------- k_flash: q128/wave-dual-subtile, 4-way split-KV, Sigma-free softmax ----------
// (R12 proven config: grid 512, 64-key tiles, 76KB LDS, 2 blocks/CU, FETCH ~11MB) + T5 setprio
__global__ __launch_bounds__(256, 2) void k_flash(const unsigned short* __restrict__ qkbf,
                                                  const unsigned short* __restrict__ svT,
                                                  unsigned short* __restrict__ part_acc,
                                                  float* __restrict__ part_ml)
{
    int bid = blockIdx.x;
    int b = bid & 3;
    int rest = bid >> 2;
    int qg = rest & 31;
    int s_id = rest >> 5;              // 0..3
    int lo = s_id * 16;
    int hi = lo + 16 > 63 ? 63 : lo + 16;
    int tid = threadIdx.x, w = tid >> 6, lane = tid & 63, lg = lane >> 4, lr = lane & 15;
    int q0 = qg * 128 + w * 16;        // sub u adds u*64

    __shared__ unsigned short k_lds[2][64 * 256];   // 32KB each; rows reused as P post-bar1
    __shared__ unsigned short sv_lds[96 * 64];      // 12KB single

    const unsigned short* qkb = qkbf + (size_t)b * NPAD2 * CI;
    const unsigned short* svb = svT + (size_t)b * NKP * NPAD;

    bf16x8 qa[2][8];
#pragma unroll
    for (int u = 0; u < 2; ++u)
#pragma unroll
        for (int s = 0; s < 8; ++s)
            qa[u][s] = *reinterpret_cast<const bf16x8*>(
                qkb + (size_t)(q0 + u * 64 + lr) * CI + s * 32 + lg * 8);

    f32x4 acc[2][6];
#pragma unroll
    for (int u = 0; u < 2; ++u)
#pragma unroll
        for (int jt = 0; jt < 6; ++jt) acc[u][jt] = (f32x4){0.f, 0.f, 0.f, 0.f};
    float m_run[2][4];
#pragma unroll
    for (int u = 0; u < 2; ++u)
#pragma unroll
        for (int r = 0; r < 4; ++r) m_run[u][r] = -1e30f;

    auto stageK = [&](int t, int bi) {
#pragma unroll
        for (int j = 0; j < 8; ++j) {
            int r = w * 16 + j * 2 + (lane >> 5);
            int c_hw = ((lane & 31) * 8) ^ ((r & 7) << 3);
            gll16(qkb + (size_t)(t * 64 + r) * CI + c_hw,
                  &k_lds[bi][(w * 16 + j * 2) * 256]);
        }
    };
    auto stageSV = [&](int t) {
#pragma unroll
        for (int j = 0; j < 3; ++j) {
            int k = w * 24 + j * 8 + (lane >> 3);
            int m_hw = ((lane & 7) * 8) ^ ((k & 7) << 3);
            gll16(svb + (size_t)k * NPAD + t * 64 + m_hw,
                  &sv_lds[(w * 24 + j * 8) * 64]);
        }
    };

    stageK(lo, 0);
    stageSV(lo);
    __syncthreads();

    for (int t = lo; t < hi; ++t) {
        int bi = (t - lo) & 1;
        int mbase = t * 64;
        if (t + 1 < hi) stageK(t + 1, bi ^ 1);   // prefetch next K (other buffer)

        f32x4 s_acc[2][4];
#pragma unroll
        for (int u = 0; u < 2; ++u)
#pragma unroll
            for (int tt = 0; tt < 4; ++tt) s_acc[u][tt] = (f32x4){0.f, 0.f, 0.f, 0.f};
        __builtin_amdgcn_s_setprio(1);
#pragma unroll
        for (int s = 0; s < 8; ++s) {
            bf16x8 kf[4];
#pragma unroll
            for (int tt = 0; tt < 4; ++tt) {
                int row = tt * 16 + lr;
                int hw = (s * 32 + lg * 8) ^ ((row & 7) << 3);
                kf[tt] = *reinterpret_cast<const bf16x8*>(&k_lds[bi][row * 256 + hw]);
            }
#pragma unroll
            for (int tt = 0; tt < 4; ++tt) {
                s_acc[0][tt] = MFMA16(qa[0][s], kf[tt], s_acc[0][tt]);
                s_acc[1][tt] = MFMA16(qa[1][s], kf[tt], s_acc[1][tt]);
            }
        }
        __builtin_amdgcn_s_setprio(0);
        __syncthreads();   // bar1: k_lds[bi] consumed; prefetch drained

        unsigned short* pw = &k_lds[bi][w * 2048];    // 4KB per wave
        bool lastTile = (mbase + 64 > NN);
#pragma unroll
        for (int u = 0; u < 2; ++u) {
            if (lastTile) {
#pragma unroll
                for (int tt = 0; tt < 4; ++tt) {
                    bool bad = (mbase + tt * 16 + lr) >= NN;
#pragma unroll
                    for (int r = 0; r < 4; ++r) if (bad) s_acc[u][tt][r] = -1e30f;
                }
            }
            float pmax[4];
#pragma unroll
            for (int r = 0; r < 4; ++r) {
                float m0 = fmaxf(fmaxf(s_acc[u][0][r], s_acc[u][1][r]),
                                 fmaxf(s_acc[u][2][r], s_acc[u][3][r]));
#pragma unroll
                for (int off = 1; off < 16; off <<= 1) m0 = fmaxf(m0, __shfl_xor(m0, off));
                pmax[r] = m0;
            }
            bool ok = (pmax[0] - m_run[u][0] <= 8.f) && (pmax[1] - m_run[u][1] <= 8.f) &&
                      (pmax[2] - m_run[u][2] <= 8.f) && (pmax[3] - m_run[u][3] <= 8.f);
            if (!__all(ok)) {
#pragma unroll
                for (int r = 0; r < 4; ++r) {
                    float mn = fmaxf(m_run[u][r], pmax[r]);
                    float al = __expf(m_run[u][r] - mn);
                    m_run[u][r] = mn;
#pragma unroll
                    for (int jt = 0; jt < 6; ++jt) acc[u][jt][r] *= al;
                }
            }
            unsigned short* pu = pw + u * 1024;
#pragma unroll
            for (int tt = 0; tt < 4; ++tt) {
#pragma unroll
                for (int r = 0; r < 4; ++r) {
                    float p = __expf(s_acc[u][tt][r] - m_run[u][r]);
                    int row = lg * 4 + r, col = tt * 16 + lr;
                    pu[row * 64 + (col ^ ((row & 7) << 3))] = f2bf(p);
                }
            }
        }
        __builtin_amdgcn_s_setprio(1);
#pragma unroll
        for (int kb = 0; kb < 2; ++kb) {
            int hw = kb * 32 + lg * 8;
            int phw = hw ^ ((lr & 7) << 3);
            bf16x8 pa0 = *reinterpret_cast<const bf16x8*>(&pw[lr * 64 + phw]);
            bf16x8 pa1 = *reinterpret_cast<const bf16x8*>(&pw[1024 + lr * 64 + phw]);
#pragma unroll
            for (int jt = 0; jt < 6; ++jt) {
                int cr = jt * 16 + lr;
                bf16x8 svf = *reinterpret_cast<const bf16x8*>(
                    &sv_lds[cr * 64 + (hw ^ ((cr & 7) << 3))]);
                acc[0][jt] = MFMA16(pa0, svf, acc[0][jt]);
                acc[1][jt] = MFMA16(pa1, svf, acc[1][jt]);
            }
        }
        __builtin_amdgcn_s_setprio(0);
        __syncthreads();   // bar2: sv_lds + P consumed
        if (t + 1 < hi) stageSV(t + 1);   // lands during next QK^T
    }
    int plane = s_id * 4 + b;
    unsigned short* pa_out = part_acc + (size_t)plane * NPAD2 * 96;
    float* ml_out = part_ml + (size_t)plane * 2 * NPAD2;
#pragma unroll
    for (int u = 0; u < 2; ++u)
#pragma unroll
        for (int r = 0; r < 4; ++r) {
            int row = q0 + u * 64 + lg * 4 + r;
#pragma unroll
            for (int jt = 0; jt < 6; ++jt)
                pa_out[(size_t)row * 96 + jt * 16 + lr] = f2bf(acc[u][jt][r]);
            if (lr == 0) ml_out[row] = m_run[u][r];
            if (lr == 1) ml_out[NPAD2 + row] = acc[u][5][r];   // l = acc col 81 (fp32)
        }
}

// ---------------- k_out (fused merge, og-loop inside): 4-plane merge once, then 8x MFMA -------
__global__ __launch_bounds__(256) void k_out(const unsigned short* __restrict__ part_acc,
                                             const float* __restrict__ part_ml,
                                             const unsigned short* __restrict__ Zt,
                                             const float* __restrict__ bw,
                                             float* __restrict__ out)
{
    int b = blockIdx.y;
    int ng = blockIdx.x;
    int tid = threadIdx.x, w = tid >> 6, lane = tid & 63, lg = lane >> 4, lr = lane & 15;

    __shared__ unsigned short sn[64 * 104];   // 13.3KB, stride 104 (2-way banks = free)

    // ---- phase 1: split-softmax merge of 4 planes for rows ng*64..+63
    for (int j = tid; j < 768; j += 256) {
        int row_l = j / 12, ch = j - row_l * 12;
        int row = ng * 64 + row_l;
        float m_s[NSPLIT], l_s[NSPLIT];
        float mg = -1e30f;
#pragma unroll
        for (int s = 0; s < NSPLIT; ++s) {
            const float* ml = part_ml + (size_t)(s * 4 + b) * 2 * NPAD2;
            m_s[s] = ml[row]; l_s[s] = ml[NPAD2 + row];
            mg = fmaxf(mg, m_s[s]);
        }
        float f_s[NSPLIT], denom = 0.f;
#pragma unroll
        for (int s = 0; s < NSPLIT; ++s) { f_s[s] = __expf(m_s[s] - mg); denom += f_s[s] * l_s[s]; }
        float inv = 1.f / denom;
        float a[8];
#pragma unroll
        for (int q = 0; q < 8; ++q) a[q] = 0.f;
#pragma unroll
        for (int s = 0; s < NSPLIT; ++s) {
            us8 v = *reinterpret_cast<const us8*>(
                &part_acc[((size_t)(s * 4 + b) * NPAD2 + row) * 96 + ch * 8]);
#pragma unroll
            for (int q = 0; q < 8; ++q) a[q] += f_s[s] * bf2f(v[q]);
        }
        us8 o;
#pragma unroll
        for (int q = 0; q < 8; ++q) o[q] = f2bf(a[q] * inv);
        if (ch == 10) o[1] = 0;   // zero col 81 (the ones/l column)
        *reinterpret_cast<us8*>(&sn[row_l * 104 + ch * 8]) = o;
    }
    __syncthreads();

    // ---- phase 2: loop og: D[o][n] = sum_k Zt[o][k]*sn[n][k] + bw
    for (int og = 0; og < 8; ++og) {
        int o_row = (og * 4 + w) * 16;
        const unsigned short* za = Zt + ((size_t)b * CO + o_row + lr) * NKP + lg * 8;
        bf16x8 az[3];
#pragma unroll
        for (int ks = 0; ks < 3; ++ks) az[ks] = *reinterpret_cast<const bf16x8*>(za + ks * 32);
        f32x4 acc[4];
#pragma unroll
        for (int jn = 0; jn < 4; ++jn) acc[jn] = (f32x4){0.f, 0.f, 0.f, 0.f};
#pragma unroll
        for (int jn = 0; jn < 4; ++jn)
#pragma unroll
            for (int ks = 0; ks < 3; ++ks) {
                bf16x8 bfs = *reinterpret_cast<const bf16x8*>(
                    &sn[(jn * 16 + lr) * 104 + ks * 32 + lg * 8]);
                acc[jn] = MFMA16(az[ks], bfs, acc[jn]);
            }
#pragma unroll
        for (int r = 0; r < 4; ++r) {
            int o = o_row + lg * 4 + r;
            float bias = bw[o];
            float* orow = out + ((size_t)b * CO + o) * NN;
#pragma unroll
            for (int jn = 0; jn < 4; ++jn) {
                int n = ng * 64 + jn * 16 + lr;
                if (n < NN) orow[n] = acc[jn][r] + bias;
            }
        }
    }
}

extern "C" void kernel_launch(void* const* d_in, const int* in_sizes, int n_in,
                              void* d_out, int out_size, void* d_ws, size_t ws_size,
                              hipStream_t stream)
{
    const float* x     = (const float*)d_in[0];
    const float* Wk    = (const float*)d_in[1];
    const float* bk    = (const float*)d_in[2];
    const float* gamma = (const float*)d_in[3];
    const float* beta  = (const float*)d_in[4];
    const float* Wv    = (const float*)d_in[5];
    const float* bv    = (const float*)d_in[6];
    const float* Wv2   = (const float*)d_in[7];
    const float* bv2   = (const float*)d_in[8];
    const float* Ww    = (const float*)d_in[9];
    const float* bw    = (const float*)d_in[10];
    float* out = (float*)d_out;

    char* p = (char*)d_ws;
    unsigned short* qkbf   = (unsigned short*)p; p += (size_t)BB * NPAD2 * CI * 2;
    unsigned short* value  = (unsigned short*)p; p += (size_t)BB * NPAD * CI * 2;
    unsigned short* svT    = (unsigned short*)p; p += (size_t)BB * NKP * NPAD * 2;
    unsigned short* Wkv    = (unsigned short*)p; p += (size_t)512 * 512 * 2;
    unsigned short* Wv2b   = (unsigned short*)p; p += (size_t)256 * 256 * 2;
    unsigned short* Wwb    = (unsigned short*)p; p += (size_t)512 * 256 * 2;
    unsigned short* pooled = (unsigned short*)p; p += (size_t)BB * NKP * CI * 2;
    unsigned short* v2f    = (unsigned short*)p; p += (size_t)BB * NKP * CI * 2;
    unsigned short* Zt     = (unsigned short*)p; p += (size_t)BB * CO * NKP * 2;
    float* bias2           = (float*)p;          p += 512 * 4;
    unsigned short* part_acc = (unsigned short*)p; p += (size_t)16 * NPAD2 * 96 * 2;
    float* part_ml         = (float*)p;          p += (size_t)16 * 2 * NPAD2 * 4;

    k_prep<<<dim3(1826), 256, 0, stream>>>(Wk, bk, gamma, beta, Wv, bv, Wv2, Ww,
                                           Wkv, bias2, Wv2b, Wwb, qkbf);
    k_qkv<<<dim3(126, BB), 256, 0, stream>>>(x, Wkv, bias2, qkbf, value);
    k_pool<<<dim3(NKP, BB), 256, 0, stream>>>(value, pooled);
    k_v2<<<dim3(4, BB), 256, 0, stream>>>(pooled, Wv2b, bv2, v2f);
    k_Z<<<dim3(8, BB), 256, 0, stream>>>(Wwb, v2f, Zt);
    k_simv<<<dim3(63, BB), 256, 0, stream>>>(value, v2f, svT);
    k_flash<<<dim3(512), 256, 0, stream>>>(qkbf, svT, part_acc, part_ml);
    k_out<<<dim3(63, BB), 256, 0, stream>>>(part_acc, part_ml, Zt, bw, out);
}